// Round 6
// baseline (158.468 us; speedup 1.0000x reference)
//
#include <hip/hip_runtime.h>
#include <stdint.h>

// Problem geometry (fixed by reference):
//   preds      [8, 21, 512, 512] f32
//   embeddings [8, 128, 128, 128] f32
//   gts        [8, 512, 512] i32  (unused)
//   fsss_gts   [8, 512, 512] i32
//   pos_memory [1000, 128] f32
//   neg_memory [1000, 128] f32
//   out: scalar f32
// Downsample 512->128 nearest picks rows/cols 4i, 4j exactly.
//
// R3 post-mortem: cooperative grid.sync() ~60us/sync on MI355X -> banned.
// R4 post-mortem: ~7us per dispatch boundary; 4 dispatches = ~20us overhead.
// R5: 2 dispatches + tiny memset, using completion-counter (last block does
// the serialized tail work). No spin-waits -> no deadlock risk.
// R5 bench was an infra failure (container died pre-push); resubmitting.

#define NPOS  131072   // 8*128*128
#define NBLK  512      // NPOS / 256
#define MEMSZ 1000
#define KANC  100      // MEM/10
#define KPN   333      // MEM/3
#define SLOT_POS 100
#define SLOT_NEG 433
#define FIX_SCALE 1099511627776.0        // 2^40
#define INV_FIX   (1.0 / 1099511627776.0)

// ws byte layout
#define OFF_FLAGS   0          // 131072 B
#define OFF_COUNTS  131072     // 3*512*4 = 6144 B
#define OFF_IDX     137216     // 768*4   = 3072 B
#define OFF_TOTALS  140288     // 16 B
#define OFF_ACCUM   140304     // 4*3*128*8 = 12288 B   (8-aligned)
#define OFF_CTRS    152592     // 2*4 B
#define ZERO_BASE   OFF_ACCUM
#define ZERO_BYTES  (12288 + 8)

// ================= KA: mask + counts; last block scans + selects =================
__global__ __launch_bounds__(256) void mask_select_kernel(
    const float* __restrict__ preds,
    const int* __restrict__ fsss,
    uint8_t* __restrict__ flags,
    int* __restrict__ blockCounts,
    int* __restrict__ idx,
    int* __restrict__ totals,
    unsigned int* __restrict__ counterA)
{
    const int tid = threadIdx.x, blk = blockIdx.x;
    const int lane = tid & 63, wave = tid >> 6;
    const int n = blk * 256 + tid;
    const int b = n >> 14;
    const int ij = n & 16383;
    const int row = (ij >> 7) << 2;
    const int col = (ij & 127) << 2;

    const float* p = preds + (size_t)b * 21 * 262144 + (size_t)row * 512 + col;
    float best = p[0];
    int bc = 0;
#pragma unroll
    for (int c = 1; c < 21; ++c) {
        float v = p[(size_t)c * 262144];
        if (v > best) { best = v; bc = c; }   // strict > = first-max (jnp.argmax)
    }
    const int fv = fsss[(size_t)b * 262144 + (size_t)row * 512 + col];

    const bool pm = (bc != 0);
    const bool fm = (fv != 0) && (fv != 255);
    const int myflag = (int)(pm && fm)                // bit0: anchor
                     | ((int)(!pm && fm) << 1)        // bit1: positive
                     | ((int)(pm && (fv == 0)) << 2); // bit2: negative
    flags[n] = (uint8_t)myflag;

    __shared__ int s_i[12];
#pragma unroll
    for (int cat = 0; cat < 3; ++cat) {
        unsigned long long m = __ballot((myflag >> cat) & 1);
        if (lane == 0) s_i[cat * 4 + wave] = (int)__popcll(m);
    }
    __syncthreads();
    if (tid < 3)
        blockCounts[tid * NBLK + blk] =
            s_i[tid * 4] + s_i[tid * 4 + 1] + s_i[tid * 4 + 2] + s_i[tid * 4 + 3];

    // ---- release our writes, then completion count ----
    __threadfence();
    __syncthreads();
    __shared__ int s_fin;
    if (tid == 0) {
        unsigned old = atomicAdd(counterA, 1u);
        s_fin = (old == NBLK - 1) ? 1 : 0;
    }
    __syncthreads();
    if (!s_fin) return;           // block-uniform exit
    __threadfence();              // acquire: other blocks' flags/counts now visible

    // ---- finisher: exclusive prefix over 512 block counts per cat ----
    __shared__ int s_pre[3 * NBLK];   // 6 KB
    __shared__ int s_w[4];
#pragma unroll 1
    for (int cat = 0; cat < 3; ++cat) {
        const int c0 = blockCounts[cat * NBLK + 2 * tid];
        const int c1 = blockCounts[cat * NBLK + 2 * tid + 1];
        const int pairsum = c0 + c1;
        int incl = pairsum;
#pragma unroll
        for (int off = 1; off < 64; off <<= 1) {
            int v = __shfl_up(incl, off, 64);
            if (lane >= off) incl += v;
        }
        if (lane == 63) s_w[wave] = incl;
        __syncthreads();
        int woff = 0;
#pragma unroll
        for (int w = 0; w < 4; ++w) if (w < wave) woff += s_w[w];
        const int excl0 = woff + incl - pairsum;
        s_pre[cat * NBLK + 2 * tid]     = excl0;
        s_pre[cat * NBLK + 2 * tid + 1] = excl0 + c0;
        if (tid == 0) totals[cat] = s_w[0] + s_w[1] + s_w[2] + s_w[3];
        __syncthreads();
    }

    // ---- first-k selection: walk flag bytes (u64 chunks) for contributing blocks ----
    const int kcap[3]  = {KANC, KPN, KPN};
    const int basec[3] = {0, SLOT_POS, SLOT_NEG};
#pragma unroll 1
    for (int cat = 0; cat < 3; ++cat) {
        const int cap = kcap[cat];
#pragma unroll 1
        for (int h = 0; h < 2; ++h) {
            const int bb = 2 * tid + h;
            int rank = s_pre[cat * NBLK + bb];
            if (rank >= cap) continue;
            const unsigned long long* f8 =
                (const unsigned long long*)(flags + (size_t)bb * 256);
#pragma unroll 1
            for (int k8 = 0; k8 < 32 && rank < cap; ++k8) {
                unsigned long long m = (f8[k8] >> cat) & 0x0101010101010101ull;
                while (m) {
                    const int bit = __ffsll((long long)m) - 1;
                    idx[basec[cat] + rank] = bb * 256 + k8 * 8 + (bit >> 3);
                    if (++rank >= cap) break;
                    m &= m - 1;
                }
            }
        }
    }
}

// ========== KB: gather+normalize -> fixed-point accum; last block finalizes ==========
// blocks 0..382: 2 slots each.  blocks 383..398: untouched-memory-row tails.
__global__ __launch_bounds__(256) void gather_final_kernel(
    const float* __restrict__ emb,
    const float* __restrict__ posMem,
    const float* __restrict__ negMem,
    const int* __restrict__ idx,
    const int* __restrict__ totals,
    unsigned long long* __restrict__ accum,   // [4 shadows][3 cats][128]
    unsigned int* __restrict__ counterB,
    float* __restrict__ out)
{
    const int tid = threadIdx.x, blk = blockIdx.x;
    const int lane = tid & 63, wave = tid >> 6;
    const int d = tid & 127;
    const int A = min(KANC, totals[0]);
    const int P = min(KPN, totals[1]);
    const int Q = min(KPN, totals[2]);

    if (blk < 383) {
        const int half = tid >> 7;
        const int slot = blk * 2 + half;      // 0..765
        int cat; bool valid;
        if (slot < SLOT_POS)      { cat = 0; valid = slot < A; }
        else if (slot < SLOT_NEG) { cat = 1; valid = (slot - SLOT_POS) < P; }
        else                      { cat = 2; valid = (slot - SLOT_NEG) < Q; }

        float v = 0.f;
        if (valid) {
            const int nn = idx[slot];
            v = emb[((size_t)(nn >> 14) * 128 + d) * 16384 + (nn & 16383)];
        }
        float sq = v * v;
#pragma unroll
        for (int off = 1; off < 64; off <<= 1) sq += __shfl_xor(sq, off, 64);
        __shared__ float s_f[4];
        if (lane == 0) s_f[wave] = sq;
        __syncthreads();
        const float nrm2 = s_f[half * 2] + s_f[half * 2 + 1];
        if (valid) {
            const float scale = 1.0f / fmaxf(sqrtf(nrm2), 1e-12f);
            const long long fx =
                (long long)llrint((double)v * (double)scale * FIX_SCALE);
            atomicAdd(&accum[(((blk & 3) * 3 + cat) << 7) + d],
                      (unsigned long long)fx);
        }
    } else {
        const int t = blk - 383;
        const int memSel = t >> 3;            // 0=pos, 1=neg
        const int part = t & 7;
        const float* mem = memSel ? negMem : posMem;
        const int cnt = memSel ? Q : P;       // rows [0,cnt) replaced by selections
        const int rowHalf = tid >> 7;
        const int m0 = part * 125;
        double acc = 0.0;
        for (int r = rowHalf; r < 125; r += 2) {
            const int m = m0 + r;
            if (m >= cnt) acc += (double)mem[(size_t)m * 128 + d];
        }
        const long long fx = (long long)llrint(acc * FIX_SCALE);
        atomicAdd(&accum[(((blk & 3) * 3 + (memSel ? 2 : 1)) << 7) + d],
                  (unsigned long long)fx);
    }

    // ---- release, completion count ----
    __threadfence();
    __syncthreads();
    __shared__ int s_fin;
    if (tid == 0) {
        unsigned old = atomicAdd(counterB, 1u);
        s_fin = (old == 398) ? 1 : 0;
    }
    __syncthreads();
    if (!s_fin) return;
    __threadfence();

    // ---- finisher: final dot + relu ----
    __shared__ double s_d[2];
    if (tid < 128) {
        double anc = 0.0, pos = 0.0, neg = 0.0;
#pragma unroll
        for (int s = 0; s < 4; ++s) {
            anc += (double)(long long)accum[((s * 3 + 0) << 7) + tid];
            pos += (double)(long long)accum[((s * 3 + 1) << 7) + tid];
            neg += (double)(long long)accum[((s * 3 + 2) << 7) + tid];
        }
        double prod = anc * (pos - neg) * (INV_FIX * INV_FIX);
#pragma unroll
        for (int off = 1; off < 64; off <<= 1) prod += __shfl_xor(prod, off, 64);
        if (lane == 0) s_d[wave] = prod;
    }
    __syncthreads();
    if (tid == 0) {
        const double red = s_d[0] + s_d[1];
        const double nAnc = (A > 0) ? (double)A : 1.0;
        const double vv = red / (nAnc * (double)MEMSZ) + 0.2;
        out[0] = (float)(vv > 0.0 ? vv : 0.0);
    }
}

extern "C" void kernel_launch(void* const* d_in, const int* in_sizes, int n_in,
                              void* d_out, int out_size, void* d_ws, size_t ws_size,
                              hipStream_t stream) {
    const float* preds  = (const float*)d_in[0];
    const float* emb    = (const float*)d_in[1];
    // d_in[2] = gts, unused by the loss
    const int* fsss     = (const int*)d_in[3];
    const float* posMem = (const float*)d_in[4];
    const float* negMem = (const float*)d_in[5];
    float* out = (float*)d_out;

    char* ws = (char*)d_ws;
    uint8_t* flags      = (uint8_t*)(ws + OFF_FLAGS);
    int* blockCounts    = (int*)(ws + OFF_COUNTS);
    int* idx            = (int*)(ws + OFF_IDX);
    int* totals         = (int*)(ws + OFF_TOTALS);
    unsigned long long* accum = (unsigned long long*)(ws + OFF_ACCUM);
    unsigned int* ctrs  = (unsigned int*)(ws + OFF_CTRS);

    // zero accum + both counters every call (ws is not re-poisoned between replays)
    hipMemsetAsync(ws + ZERO_BASE, 0, ZERO_BYTES, stream);

    mask_select_kernel<<<NBLK, 256, 0, stream>>>(preds, fsss, flags, blockCounts,
                                                 idx, totals, ctrs);
    gather_final_kernel<<<399, 256, 0, stream>>>(emb, posMem, negMem, idx, totals,
                                                 accum, ctrs + 1, out);
}

// Round 7
// 50.370 us; speedup vs baseline: 3.1461x; 3.1461x over previous
//
#include <hip/hip_runtime.h>
#include <stdint.h>

// Problem geometry (fixed by reference):
//   preds      [8, 21, 512, 512] f32
//   embeddings [8, 128, 128, 128] f32
//   gts        [8, 512, 512] i32  (unused)
//   fsss_gts   [8, 512, 512] i32
//   pos_memory [1000, 128] f32
//   neg_memory [1000, 128] f32
//   out: scalar f32
// Downsample 512->128 nearest picks rows/cols 4i, 4j exactly.
//
// Ledger of structural findings:
//  R3: cooperative grid.sync() ~60us/sync on MI355X (cross-XCD) -> banned.
//  R4: 4 dispatches, owner-block selection (ballot + redundant prefix) = 41us;
//      ~5-7us per dispatch boundary.
//  R6: single-finisher serial flag-walk = ~125us tail (latency-serialized
//      cross-XCD loads) -> selection must stay with owner blocks.
//      BUT completion-counter + CHEAP finisher (12KB dot) costs <2us -> keep
//      that for the final reduction only.
//  R7: R4 structure, K4 folded into K3 (completion counter), zeroing folded
//      into K1, nontemporal streaming loads. 3 dispatches, no memset node.

#define NPOS  131072   // 8*128*128
#define NBLK  512      // NPOS / 256
#define MEMSZ 1000
#define KANC  100      // MEM/10
#define KPN   333      // MEM/3
#define SLOT_POS 100
#define SLOT_NEG 433
#define FIX_SCALE 1099511627776.0        // 2^40
#define INV_FIX   (1.0 / 1099511627776.0)

// ws byte layout
#define OFF_FLAGS   0          // 131072 B
#define OFF_COUNTS  131072     // 3*512*4 = 6144 B
#define OFF_IDX     137216     // 768*4   = 3072 B
#define OFF_TOTALS  140288     // 16 B
#define OFF_ACCUM   140304     // 4*3*128*8 = 12288 B (8-aligned)
#define OFF_CTR     152592     // 4 B

// ========= K1: argmax + masks + per-block counts; block 0 zeroes accum =========
__global__ __launch_bounds__(256) void mask_kernel(
    const float* __restrict__ preds,
    const int* __restrict__ fsss,
    uint8_t* __restrict__ flags,
    int* __restrict__ blockCounts,
    unsigned long long* __restrict__ accum,
    unsigned int* __restrict__ counterB)
{
    const int tid = threadIdx.x, blk = blockIdx.x;
    const int lane = tid & 63, wave = tid >> 6;
    const int n = blk * 256 + tid;
    const int b = n >> 14;
    const int ij = n & 16383;
    const int row = (ij >> 7) << 2;
    const int col = (ij & 127) << 2;

    const float* p = preds + (size_t)b * 21 * 262144 + (size_t)row * 512 + col;
    float best = __builtin_nontemporal_load(p);
    int bc = 0;
#pragma unroll
    for (int c = 1; c < 21; ++c) {
        float v = __builtin_nontemporal_load(p + (size_t)c * 262144);
        if (v > best) { best = v; bc = c; }   // strict > = first-max (jnp.argmax)
    }
    const int fv = __builtin_nontemporal_load(
        fsss + (size_t)b * 262144 + (size_t)row * 512 + col);

    const bool pm = (bc != 0);
    const bool fm = (fv != 0) && (fv != 255);
    const int myflag = (int)(pm && fm)                // bit0: anchor
                     | ((int)(!pm && fm) << 1)        // bit1: positive
                     | ((int)(pm && (fv == 0)) << 2); // bit2: negative
    flags[n] = (uint8_t)myflag;

    __shared__ int s_i[12];
#pragma unroll
    for (int cat = 0; cat < 3; ++cat) {
        unsigned long long m = __ballot((myflag >> cat) & 1);
        if (lane == 0) s_i[cat * 4 + wave] = (int)__popcll(m);
    }
    __syncthreads();
    if (tid < 3)
        blockCounts[tid * NBLK + blk] =
            s_i[tid * 4] + s_i[tid * 4 + 1] + s_i[tid * 4 + 2] + s_i[tid * 4 + 3];

    // zero the fixed-point accumulators + K3's completion counter every call
    // (d_ws retains previous replay's values; K3 runs after K1 in stream order)
    if (blk == 0) {
        for (int i = tid; i < 4 * 3 * 128; i += 256) accum[i] = 0ull;
        if (tid == 0) *counterB = 0u;
    }
}

// ===== K2: per-block redundant prefix + owner-block first-k select (R4 pattern) =====
__global__ __launch_bounds__(256) void select_kernel(
    const uint8_t* __restrict__ flags,
    const int* __restrict__ blockCounts,
    int* __restrict__ idx,
    int* __restrict__ totals)
{
    const int tid = threadIdx.x, blk = blockIdx.x;
    const int lane = tid & 63, wave = tid >> 6;
    __shared__ int s_i[12];

    // --- sum of counts over blocks < blk (6KB table, L2-resident; same-XCD
    // mapping as K1's writers since both launches are 512 blocks) ---
#pragma unroll
    for (int cat = 0; cat < 3; ++cat) {
        const int c0 = blockCounts[cat * NBLK + tid];
        const int c1 = blockCounts[cat * NBLK + 256 + tid];
        int v = ((tid < blk) ? c0 : 0) + ((256 + tid < blk) ? c1 : 0);
#pragma unroll
        for (int off = 1; off < 64; off <<= 1) v += __shfl_xor(v, off, 64);
        if (lane == 0) s_i[cat * 4 + wave] = v;
    }
    __syncthreads();
    int pre[3];
#pragma unroll
    for (int cat = 0; cat < 3; ++cat)
        pre[cat] = s_i[cat * 4] + s_i[cat * 4 + 1] + s_i[cat * 4 + 2] + s_i[cat * 4 + 3];
    if (blk == NBLK - 1 && tid < 3)
        totals[tid] = pre[tid] + blockCounts[tid * NBLK + NBLK - 1];
    __syncthreads();   // s_i reuse below

    // --- first-k selection via ballots; O(1) rank per thread ---
    const int n = blk * 256 + tid;
    const int f = flags[n];
    unsigned long long masks[3];
#pragma unroll
    for (int cat = 0; cat < 3; ++cat) {
        masks[cat] = __ballot((f >> cat) & 1);
        if (lane == 0) s_i[cat * 4 + wave] = (int)__popcll(masks[cat]);
    }
    __syncthreads();
    const int kcap[3]  = {KANC, KPN, KPN};
    const int basec[3] = {0, SLOT_POS, SLOT_NEG};
#pragma unroll
    for (int cat = 0; cat < 3; ++cat) {
        if ((f >> cat) & 1) {
            int woff = 0;
#pragma unroll
            for (int w = 0; w < 4; ++w) if (w < wave) woff += s_i[cat * 4 + w];
            const int intra = woff + (int)__popcll(masks[cat] & ((1ull << lane) - 1ull));
            const int rank = pre[cat] + intra;
            if (rank < kcap[cat]) idx[basec[cat] + rank] = n;
        }
    }
}

// ====== K3: gather+normalize -> fixed-point accum; cheap finisher does the dot ======
// blocks 0..382: 2 slots each.  blocks 383..398: untouched-memory-row tails.
__global__ __launch_bounds__(256) void gather_final_kernel(
    const float* __restrict__ emb,
    const float* __restrict__ posMem,
    const float* __restrict__ negMem,
    const int* __restrict__ idx,
    const int* __restrict__ totals,
    unsigned long long* __restrict__ accum,   // [4 shadows][3 cats][128]
    unsigned int* __restrict__ counterB,
    float* __restrict__ out)
{
    const int tid = threadIdx.x, blk = blockIdx.x;
    const int lane = tid & 63, wave = tid >> 6;
    const int d = tid & 127;
    const int A = min(KANC, totals[0]);
    const int P = min(KPN, totals[1]);
    const int Q = min(KPN, totals[2]);

    if (blk < 383) {
        const int half = tid >> 7;
        const int slot = blk * 2 + half;      // 0..765
        int cat; bool valid;
        if (slot < SLOT_POS)      { cat = 0; valid = slot < A; }
        else if (slot < SLOT_NEG) { cat = 1; valid = (slot - SLOT_POS) < P; }
        else                      { cat = 2; valid = (slot - SLOT_NEG) < Q; }

        float v = 0.f;
        if (valid) {
            const int nn = idx[slot];
            v = emb[((size_t)(nn >> 14) * 128 + d) * 16384 + (nn & 16383)];
        }
        float sq = v * v;
#pragma unroll
        for (int off = 1; off < 64; off <<= 1) sq += __shfl_xor(sq, off, 64);
        __shared__ float s_f[4];
        if (lane == 0) s_f[wave] = sq;
        __syncthreads();
        const float nrm2 = s_f[half * 2] + s_f[half * 2 + 1];
        if (valid) {
            const float scale = 1.0f / fmaxf(sqrtf(nrm2), 1e-12f);
            const long long fx =
                (long long)llrint((double)v * (double)scale * FIX_SCALE);
            atomicAdd(&accum[(((blk & 3) * 3 + cat) << 7) + d],
                      (unsigned long long)fx);
        }
    } else {
        const int t = blk - 383;
        const int memSel = t >> 3;            // 0=pos, 1=neg
        const int part = t & 7;
        const float* mem = memSel ? negMem : posMem;
        const int cnt = memSel ? Q : P;       // rows [0,cnt) replaced by selections
        const int rowHalf = tid >> 7;
        const int m0 = part * 125;
        double acc = 0.0;
        for (int r = rowHalf; r < 125; r += 2) {
            const int m = m0 + r;
            if (m >= cnt) acc += (double)mem[(size_t)m * 128 + d];
        }
        const long long fx = (long long)llrint(acc * FIX_SCALE);
        atomicAdd(&accum[(((blk & 3) * 3 + (memSel ? 2 : 1)) << 7) + d],
                  (unsigned long long)fx);
    }

    // ---- release, completion count (cheap-finisher pattern, proven in R6-KB) ----
    __threadfence();
    __syncthreads();
    __shared__ int s_fin;
    if (tid == 0) {
        unsigned old = atomicAdd(counterB, 1u);
        s_fin = (old == 398) ? 1 : 0;
    }
    __syncthreads();
    if (!s_fin) return;
    __threadfence();

    // ---- finisher: final dot + relu (reads only 12KB accum) ----
    __shared__ double s_d[2];
    if (tid < 128) {
        double anc = 0.0, pos = 0.0, neg = 0.0;
#pragma unroll
        for (int s = 0; s < 4; ++s) {
            anc += (double)(long long)accum[((s * 3 + 0) << 7) + tid];
            pos += (double)(long long)accum[((s * 3 + 1) << 7) + tid];
            neg += (double)(long long)accum[((s * 3 + 2) << 7) + tid];
        }
        double prod = anc * (pos - neg) * (INV_FIX * INV_FIX);
#pragma unroll
        for (int off = 1; off < 64; off <<= 1) prod += __shfl_xor(prod, off, 64);
        if (lane == 0) s_d[wave] = prod;
    }
    __syncthreads();
    if (tid == 0) {
        const double red = s_d[0] + s_d[1];
        const double nAnc = (A > 0) ? (double)A : 1.0;
        const double vv = red / (nAnc * (double)MEMSZ) + 0.2;
        out[0] = (float)(vv > 0.0 ? vv : 0.0);
    }
}

extern "C" void kernel_launch(void* const* d_in, const int* in_sizes, int n_in,
                              void* d_out, int out_size, void* d_ws, size_t ws_size,
                              hipStream_t stream) {
    const float* preds  = (const float*)d_in[0];
    const float* emb    = (const float*)d_in[1];
    // d_in[2] = gts, unused by the loss
    const int* fsss     = (const int*)d_in[3];
    const float* posMem = (const float*)d_in[4];
    const float* negMem = (const float*)d_in[5];
    float* out = (float*)d_out;

    char* ws = (char*)d_ws;
    uint8_t* flags      = (uint8_t*)(ws + OFF_FLAGS);
    int* blockCounts    = (int*)(ws + OFF_COUNTS);
    int* idx            = (int*)(ws + OFF_IDX);
    int* totals         = (int*)(ws + OFF_TOTALS);
    unsigned long long* accum = (unsigned long long*)(ws + OFF_ACCUM);
    unsigned int* ctr   = (unsigned int*)(ws + OFF_CTR);

    mask_kernel  <<<NBLK, 256, 0, stream>>>(preds, fsss, flags, blockCounts,
                                            accum, ctr);
    select_kernel<<<NBLK, 256, 0, stream>>>(flags, blockCounts, idx, totals);
    gather_final_kernel<<<399, 256, 0, stream>>>(emb, posMem, negMem, idx, totals,
                                                 accum, ctr, out);
}